// Round 3
// baseline (477.337 us; speedup 1.0000x reference)
//
#include <hip/hip_runtime.h>
#include <hip/hip_cooperative_groups.h>

namespace cg = cooperative_groups;

#define IN_DIM   256
#define HID_DIM  512
#define OUT_DIM  256
#define N_CHILD  8
#define BATCH    1024

#define SB    16   // samples per chunk
#define XPAD  20   // [k][s] LDS stride: 16B-aligned float4 groups, bank-spread
#define MAXCH 128  // sum ceil(n_a/16) <= (1024 + 64*15)/16 = 124 < 128

// ---------------- fused per-block chunk derivation --------------------------
// Every block recomputes the counting sort deterministically from raw ids:
// identical chunk->samples maps in all blocks, no inter-block traffic.
__device__ __forceinline__ int sort_chunk(const int* __restrict__ raw, const int c,
                                          int* s_cnt, int* s_info, int* s_wsum,
                                          int* s_sid)
{
    const int t = threadIdx.x;           // 256 threads
    const int lane = t & 63, w = t >> 6;
    if (t < 64) s_cnt[t] = 0;
    if (t == 0) { s_info[2] = 0; s_info[3] = 0; }
    __syncthreads();
    // int32 vs int64 agent_indices: odd 32-bit words of first 1024 ints
    if (raw[2 * t + 1] != 0 || raw[2 * (t + 256) + 1] != 0) s_info[3] = 1;
    __syncthreads();
    const int is32 = s_info[3];
    int myid[4];
    #pragma unroll
    for (int j = 0; j < 4; ++j) {
        const int i = t * 4 + j;
        const int v = (is32 ? raw[i] : raw[2 * i]) & 63;
        myid[j] = v;
        atomicAdd(&s_cnt[v], 1);
    }
    __syncthreads();
    if (t < 64) {                        // wave 0: chunk table prefix scan
        const int ca  = s_cnt[t];
        const int nch = (ca + SB - 1) / SB;
        int sn = nch;
        #pragma unroll
        for (int d = 1; d < 64; d <<= 1) {
            const int v = __shfl_up(sn, d);
            if (lane >= d) sn += v;
        }
        const int chb = sn - nch;        // first chunk of agent t
        if (c >= chb && c < chb + nch) { // exactly one agent claims chunk c
            s_info[0] = t;
            const int p = (c - chb) * SB;
            s_info[1] = p;
            s_info[2] = (ca - p < SB) ? (ca - p) : SB;
        }
    }
    __syncthreads();
    const int len = s_info[2];
    if (len == 0) return 0;              // c >= total chunks
    const int a = s_info[0], p = s_info[1];
    int m = 0;
    #pragma unroll
    for (int j = 0; j < 4; ++j) if (myid[j] == a) ++m;
    int inc = m;                         // inclusive wave scan of match counts
    #pragma unroll
    for (int d = 1; d < 64; d <<= 1) {
        const int v = __shfl_up(inc, d);
        if (lane >= d) inc += v;
    }
    if (lane == 63) s_wsum[w] = inc;
    __syncthreads();
    int base = inc - m;                  // exclusive rank base
    #pragma unroll
    for (int ww = 0; ww < 4; ++ww) if (ww < w) base += s_wsum[ww];
    #pragma unroll
    for (int j = 0; j < 4; ++j)
        if (myid[j] == a) {              // stable rank among agent's samples
            const int r = (base++) - p;
            if (r >= 0 && r < SB) s_sid[r] = t * 4 + j;
        }
    __syncthreads();
    if (t >= len && t < SB) s_sid[t] = s_sid[len - 1];   // pad = dup
    __syncthreads();
    return len;
}

// ---------------- fused kernel ----------------------------------------------
// grid (MAXCH, 8) = 1024 blocks, 256 thr, 36.4 KB LDS -> exactly 4 blk/CU,
// all co-resident (cooperative). mode 0: phase1 -> grid.sync -> phase2.
// mode 1/2: fallback split (plain launches) if cooperative capture rejected.
//
// Register blocking 8 cols x 4 samples per lane (1.5 B LDS / FMA, was 2.0):
//   cg = t&7 (8 col-groups of 8), kq = (t>>3)&7 (8-way K, lane bits 3-5,
//   shuffle-reducible), w = t>>6 (4 samples each).
// wS XOR-swizzle: float4 slot' = slot ^ (row&15) -> kq lanes hit 8 distinct
// bank-groups (conflict-free); xv reads bank-spread by XPAD=20, broadcast
// across cg.
extern "C" __global__ __launch_bounds__(256, 4)
void fused(const float* __restrict__ x, const float* __restrict__ W1,
           const float* __restrict__ b1, const float* __restrict__ W2,
           const float* __restrict__ b2, const float* __restrict__ rw,
           const int* __restrict__ raw, float* __restrict__ h_out,
           float* __restrict__ r_part, float* __restrict__ o_out,
           float* __restrict__ r_out, int mode)
{
    __shared__ float sm[IN_DIM * XPAD];  // 20 KB: xT (ph1) / hT (ph2, 5 KB)
    __shared__ float wS[64 * 64];        // 16 KB W tile (swizzled)
    __shared__ int s_cnt[64], s_info[4], s_wsum[4], s_sid[SB];

    const int c = blockIdx.x;
    const int t = threadIdx.x;
    const int len = sort_chunk(raw, c, s_cnt, s_info, s_wsum, s_sid);
    const int a   = s_info[0];

    const int cg = t & 7;
    const int kq = (t >> 3) & 7;
    const int w  = t >> 6;
    const bool act = (w * 4) < len;
    const int sr  = t >> 4;              // staging row base (0..15)
    const int gc4 = (t & 15) * 4;        // global staging col
    const int slt = ((t & 15) ^ sr) * 4; // swizzled LDS staging col

    // ======================= PHASE 1: H + router partials ===================
    if (mode != 2 && len > 0) {
        const int bcol = blockIdx.y * 64;
        const float* Wb = W1 + (size_t)a * IN_DIM * HID_DIM + bcol;
        #define WLD(P,I) (*(const float4*)(Wb + (size_t)((P)*64 + sr + (I)*16) * HID_DIM + gc4))

        float4 wr0 = WLD(0,0), wr1 = WLD(0,1), wr2 = WLD(0,2), wr3 = WLD(0,3);

        #pragma unroll
        for (int s = 0; s < SB; ++s)
            sm[t * XPAD + s] = x[(size_t)s_sid[s] * IN_DIM + t];  // coalesced

        float acc[32];
        #pragma unroll
        for (int i = 0; i < 32; ++i) acc[i] = 0.f;

        for (int p = 0; p < IN_DIM / 64; ++p) {
            __syncthreads();             // wS free; covers sm staging at p==0
            *(float4*)(&wS[(sr +  0) * 64 + slt]) = wr0;
            *(float4*)(&wS[(sr + 16) * 64 + slt]) = wr1;
            *(float4*)(&wS[(sr + 32) * 64 + slt]) = wr2;
            *(float4*)(&wS[(sr + 48) * 64 + slt]) = wr3;
            __syncthreads();
            if (p < 3) {                 // prefetch next tile -> regs
                wr0 = WLD(p+1,0); wr1 = WLD(p+1,1);
                wr2 = WLD(p+1,2); wr3 = WLD(p+1,3);
            }
            if (act) {
                #pragma unroll
                for (int i = 0; i < 8; ++i) {
                    const int row = i * 8 + kq;
                    const int rs  = row & 15;
                    const float4 wv0 = *(const float4*)(&wS[row * 64 + ((2*cg    ^ rs) * 4)]);
                    const float4 wv1 = *(const float4*)(&wS[row * 64 + (((2*cg+1) ^ rs) * 4)]);
                    const float4 xv  = *(const float4*)(&sm[(p * 64 + row) * XPAD + w * 4]);
                    const float wa[8] = {wv0.x, wv0.y, wv0.z, wv0.w,
                                         wv1.x, wv1.y, wv1.z, wv1.w};
                    const float xa[4] = {xv.x, xv.y, xv.z, xv.w};
                    #pragma unroll
                    for (int cc = 0; cc < 8; ++cc)
                        #pragma unroll
                        for (int s = 0; s < 4; ++s)
                            acc[cc * 4 + s] = fmaf(wa[cc], xa[s], acc[cc * 4 + s]);
                }
            }
        }
        #undef WLD

        if (act) {
            #pragma unroll
            for (int i = 0; i < 32; ++i) {   // reduce over kq (lane bits 3-5)
                acc[i] += __shfl_xor(acc[i], 8);
                acc[i] += __shfl_xor(acc[i], 16);
                acc[i] += __shfl_xor(acc[i], 32);
            }
            if (kq == 0) {
                const float4 bv0 = *(const float4*)(b1 + a * HID_DIM + bcol + cg * 8);
                const float4 bv1 = *(const float4*)(b1 + a * HID_DIM + bcol + cg * 8 + 4);
                const float ba[8] = {bv0.x, bv0.y, bv0.z, bv0.w,
                                     bv1.x, bv1.y, bv1.z, bv1.w};
                float hv[32];
                #pragma unroll
                for (int cc = 0; cc < 8; ++cc)
                    #pragma unroll
                    for (int s = 0; s < 4; ++s)
                        hv[cc * 4 + s] = fmaxf(acc[cc * 4 + s] + ba[cc], 0.f);

                #pragma unroll
                for (int s = 0; s < 4; ++s) { // dup-slot writes identical
                    float* hb = h_out + (size_t)s_sid[w * 4 + s] * HID_DIM + bcol + cg * 8;
                    *(float4*)(hb)     = make_float4(hv[0*4+s], hv[1*4+s], hv[2*4+s], hv[3*4+s]);
                    *(float4*)(hb + 4) = make_float4(hv[4*4+s], hv[5*4+s], hv[6*4+s], hv[7*4+s]);
                }

                float rp[32];                 // router partials [s][ch]
                #pragma unroll
                for (int i = 0; i < 32; ++i) rp[i] = 0.f;
                const float* rwa = rw + (size_t)a * HID_DIM * N_CHILD
                                      + (size_t)(bcol + cg * 8) * N_CHILD;
                #pragma unroll
                for (int j = 0; j < 8; ++j)
                    #pragma unroll
                    for (int ch = 0; ch < 8; ++ch) {
                        const float rv = rwa[j * N_CHILD + ch];
                        #pragma unroll
                        for (int s = 0; s < 4; ++s)
                            rp[s * 8 + ch] = fmaf(hv[j * 4 + s], rv, rp[s * 8 + ch]);
                    }
                #pragma unroll
                for (int i = 0; i < 32; ++i) { // reduce over cg (lane bits 0-2)
                    rp[i] += __shfl_xor(rp[i], 1);
                    rp[i] += __shfl_xor(rp[i], 2);
                    rp[i] += __shfl_xor(rp[i], 4);
                }
                if (cg == 0) {               // direct partial store, no atomics
                    float* rb = r_part + ((size_t)c * 8 + blockIdx.y) * 128 + w * 32;
                    #pragma unroll
                    for (int s4 = 0; s4 < 8; ++s4)
                        *(float4*)(rb + s4 * 4) = make_float4(rp[s4*4+0], rp[s4*4+1],
                                                              rp[s4*4+2], rp[s4*4+3]);
                }
            }
        }
    }

    // ======================= grid-wide barrier ==============================
    if (mode == 0) {
        __threadfence();
        cg::this_grid().sync();
        __threadfence();
    }

    // ======================= PHASE 2: OUT + router final ====================
    if (mode != 1 && len > 0) {
        if (blockIdx.y < 4) {            // 64-col output tiles, full K=512
            const int bcol = blockIdx.y * 64;
            const float* Wb = W2 + (size_t)a * HID_DIM * OUT_DIM + bcol;
            const int hrow = t & 63;
            const int hsb  = (t >> 6) * 4;
            #define WLD2(P,I) (*(const float4*)(Wb + (size_t)((P)*64 + sr + (I)*16) * OUT_DIM + gc4))
            #define HLD(P,J)  (h_out[(size_t)s_sid[hsb + (J)] * HID_DIM + (P)*64 + hrow])

            float4 wr0 = WLD2(0,0), wr1 = WLD2(0,1), wr2 = WLD2(0,2), wr3 = WLD2(0,3);
            float  hr0 = HLD(0,0),  hr1 = HLD(0,1),  hr2 = HLD(0,2),  hr3 = HLD(0,3);

            float acc[32];
            #pragma unroll
            for (int i = 0; i < 32; ++i) acc[i] = 0.f;

            for (int p = 0; p < HID_DIM / 64; ++p) {
                __syncthreads();
                sm[hrow * XPAD + hsb + 0] = hr0;
                sm[hrow * XPAD + hsb + 1] = hr1;
                sm[hrow * XPAD + hsb + 2] = hr2;
                sm[hrow * XPAD + hsb + 3] = hr3;
                *(float4*)(&wS[(sr +  0) * 64 + slt]) = wr0;
                *(float4*)(&wS[(sr + 16) * 64 + slt]) = wr1;
                *(float4*)(&wS[(sr + 32) * 64 + slt]) = wr2;
                *(float4*)(&wS[(sr + 48) * 64 + slt]) = wr3;
                __syncthreads();
                if (p < 7) {
                    wr0 = WLD2(p+1,0); wr1 = WLD2(p+1,1);
                    wr2 = WLD2(p+1,2); wr3 = WLD2(p+1,3);
                    hr0 = HLD(p+1,0);  hr1 = HLD(p+1,1);
                    hr2 = HLD(p+1,2);  hr3 = HLD(p+1,3);
                }
                if (act) {
                    #pragma unroll
                    for (int i = 0; i < 8; ++i) {
                        const int row = i * 8 + kq;
                        const int rs  = row & 15;
                        const float4 wv0 = *(const float4*)(&wS[row * 64 + ((2*cg    ^ rs) * 4)]);
                        const float4 wv1 = *(const float4*)(&wS[row * 64 + (((2*cg+1) ^ rs) * 4)]);
                        const float4 xv  = *(const float4*)(&sm[row * XPAD + w * 4]);
                        const float wa[8] = {wv0.x, wv0.y, wv0.z, wv0.w,
                                             wv1.x, wv1.y, wv1.z, wv1.w};
                        const float xa[4] = {xv.x, xv.y, xv.z, xv.w};
                        #pragma unroll
                        for (int cc = 0; cc < 8; ++cc)
                            #pragma unroll
                            for (int s = 0; s < 4; ++s)
                                acc[cc * 4 + s] = fmaf(wa[cc], xa[s], acc[cc * 4 + s]);
                    }
                }
            }
            #undef WLD2
            #undef HLD

            if (act) {
                #pragma unroll
                for (int i = 0; i < 32; ++i) {  // reduce over kq
                    acc[i] += __shfl_xor(acc[i], 8);
                    acc[i] += __shfl_xor(acc[i], 16);
                    acc[i] += __shfl_xor(acc[i], 32);
                }
                if (kq == 0) {
                    const float4 bv0 = *(const float4*)(b2 + a * OUT_DIM + bcol + cg * 8);
                    const float4 bv1 = *(const float4*)(b2 + a * OUT_DIM + bcol + cg * 8 + 4);
                    #pragma unroll
                    for (int s = 0; s < 4; ++s) {
                        const int g = w * 4 + s;
                        if (g < len) {          // strict gating: one writer/row
                            float* op = o_out + (size_t)s_sid[g] * OUT_DIM + bcol + cg * 8;
                            *(float4*)(op)     = make_float4(acc[0*4+s] + bv0.x, acc[1*4+s] + bv0.y,
                                                             acc[2*4+s] + bv0.z, acc[3*4+s] + bv0.w);
                            *(float4*)(op + 4) = make_float4(acc[4*4+s] + bv1.x, acc[5*4+s] + bv1.y,
                                                             acc[6*4+s] + bv1.z, acc[7*4+s] + bv1.w);
                        }
                    }
                }
            }
        } else if (blockIdx.y == 4) {    // router final: sum 8 partials
            if (t < 128) {
                const int s = t >> 3;
                if (s < len) {
                    float sum = 0.f;
                    #pragma unroll
                    for (int yy = 0; yy < 8; ++yy)
                        sum += r_part[((size_t)c * 8 + yy) * 128 + t];
                    r_out[(size_t)s_sid[s] * N_CHILD + (t & 7)] = sum;
                }
            }
        }
    }
}

extern "C" void kernel_launch(void* const* d_in, const int* in_sizes, int n_in,
                              void* d_out, int out_size, void* d_ws, size_t ws_size,
                              hipStream_t stream) {
    const float* x  = (const float*)d_in[0];
    const float* W1 = (const float*)d_in[1];
    const float* b1 = (const float*)d_in[2];
    const float* W2 = (const float*)d_in[3];
    const float* b2 = (const float*)d_in[4];
    const float* rw = (const float*)d_in[5];
    const int* raw  = (const int*)d_in[6];

    float* r_part = (float*)d_ws;        // [MAXCH][8][16][8] = 512 KB

    float* out   = (float*)d_out;
    float* h_out = out;                                   // [B, HID]
    float* o_out = h_out + (size_t)BATCH * HID_DIM;       // [B, OUT]
    float* r_out = o_out + (size_t)BATCH * OUT_DIM;       // [B, C]

    int mode = 0;
    void* args[] = {(void*)&x, (void*)&W1, (void*)&b1, (void*)&W2, (void*)&b2,
                    (void*)&rw, (void*)&raw, (void*)&h_out, (void*)&r_part,
                    (void*)&o_out, (void*)&r_out, (void*)&mode};
    hipError_t e = hipLaunchCooperativeKernel((const void*)fused, dim3(MAXCH, 8),
                                              dim3(256), args, 0, stream);
    if (e != hipSuccess) {               // capture rejected cooperative launch:
        (void)hipGetLastError();         // clear error, fall back to 2 passes
        hipLaunchKernelGGL(fused, dim3(MAXCH, 8), dim3(256), 0, stream,
                           x, W1, b1, W2, b2, rw, raw, h_out, r_part,
                           o_out, r_out, 1);
        hipLaunchKernelGGL(fused, dim3(MAXCH, 8), dim3(256), 0, stream,
                           x, W1, b1, W2, b2, rw, raw, h_out, r_part,
                           o_out, r_out, 2);
    }
}

// Round 4
// 153.813 us; speedup vs baseline: 3.1034x; 3.1034x over previous
//
#include <hip/hip_runtime.h>

#define IN_DIM   256
#define HID_DIM  512
#define OUT_DIM  256
#define N_CHILD  8
#define BATCH    1024

#define SB    16   // samples per chunk
#define XPAD  20   // [k][s] LDS stride: 16B-aligned float4 groups, bank-spread
#define MAXCH 128  // sum ceil(n_a/16) <= (1024 + 64*15)/16 = 124 < 128

// ---------------- fused per-block chunk derivation --------------------------
// Every block recomputes the counting sort deterministically from raw ids:
// identical chunk->samples maps in all blocks, no inter-block traffic.
__device__ __forceinline__ int sort_chunk(const int* __restrict__ raw, const int c,
                                          int* s_cnt, int* s_info, int* s_wsum,
                                          int* s_sid)
{
    const int t = threadIdx.x;           // 256 threads
    const int lane = t & 63, w = t >> 6;
    if (t < 64) s_cnt[t] = 0;
    if (t == 0) { s_info[2] = 0; s_info[3] = 0; }
    __syncthreads();
    // int32 vs int64 agent_indices: odd 32-bit words of first 1024 ints
    if (raw[2 * t + 1] != 0 || raw[2 * (t + 256) + 1] != 0) s_info[3] = 1;
    __syncthreads();
    const int is32 = s_info[3];
    int myid[4];
    #pragma unroll
    for (int j = 0; j < 4; ++j) {
        const int i = t * 4 + j;
        const int v = (is32 ? raw[i] : raw[2 * i]) & 63;
        myid[j] = v;
        atomicAdd(&s_cnt[v], 1);
    }
    __syncthreads();
    if (t < 64) {                        // wave 0: chunk table prefix scan
        const int ca  = s_cnt[t];
        const int nch = (ca + SB - 1) / SB;
        int sn = nch;
        #pragma unroll
        for (int d = 1; d < 64; d <<= 1) {
            const int v = __shfl_up(sn, d);
            if (lane >= d) sn += v;
        }
        const int chb = sn - nch;        // first chunk of agent t
        if (c >= chb && c < chb + nch) { // exactly one agent claims chunk c
            s_info[0] = t;
            const int p = (c - chb) * SB;
            s_info[1] = p;
            s_info[2] = (ca - p < SB) ? (ca - p) : SB;
        }
    }
    __syncthreads();
    const int len = s_info[2];
    if (len == 0) return 0;              // c >= total chunks
    const int a = s_info[0], p = s_info[1];
    int m = 0;
    #pragma unroll
    for (int j = 0; j < 4; ++j) if (myid[j] == a) ++m;
    int inc = m;                         // inclusive wave scan of match counts
    #pragma unroll
    for (int d = 1; d < 64; d <<= 1) {
        const int v = __shfl_up(inc, d);
        if (lane >= d) inc += v;
    }
    if (lane == 63) s_wsum[w] = inc;
    __syncthreads();
    int base = inc - m;                  // exclusive rank base
    #pragma unroll
    for (int ww = 0; ww < 4; ++ww) if (ww < w) base += s_wsum[ww];
    #pragma unroll
    for (int j = 0; j < 4; ++j)
        if (myid[j] == a) {              // stable rank among agent's samples
            const int r = (base++) - p;
            if (r >= 0 && r < SB) s_sid[r] = t * 4 + j;
        }
    __syncthreads();
    if (t >= len && t < SB) s_sid[t] = s_sid[len - 1];   // pad = dup
    __syncthreads();
    return len;
}

// ---------------- K1: H = relu(X @ W1[a] + b1[a]); router partials -> ws ----
// grid (MAXCH, 8 tiles of 64 cols), 256 thr, 36.4 KB LDS -> 4 blk/CU, all
// 1024 blocks co-resident. 8x4 register blocking (1.5 B LDS / FMA):
//   cg = t&7 (8 col-groups of 8), kq = (t>>3)&7 (8-way K, lane bits 3-5),
//   w = t>>6 (4 samples each).
// wS XOR-swizzle (slot' = slot ^ (row&15), float4 units): conflict-free wv
// reads (verified round 3: SQ_LDS_BANK_CONFLICT ~0); xv spread by XPAD=20.
extern "C" __global__ __launch_bounds__(256, 4)
void k1_mlp1(const float* __restrict__ x, const float* __restrict__ W1,
             const float* __restrict__ b1, const float* __restrict__ rw,
             const int* __restrict__ raw,
             float* __restrict__ h_out, float* __restrict__ r_part)
{
    __shared__ float sm[IN_DIM * XPAD];  // 20 KB xT [k][s]
    __shared__ float wS[64 * 64];        // 16 KB W tile (swizzled)
    __shared__ int s_cnt[64], s_info[4], s_wsum[4], s_sid[SB];

    const int c = blockIdx.x;
    const int t = threadIdx.x;
    const int len = sort_chunk(raw, c, s_cnt, s_info, s_wsum, s_sid);
    if (len == 0) return;
    const int a = s_info[0];

    const int cg = t & 7;
    const int kq = (t >> 3) & 7;
    const int w  = t >> 6;
    const bool act = (w * 4) < len;
    const int sr  = t >> 4;              // staging row base (0..15)
    const int gc4 = (t & 15) * 4;        // global staging col
    const int slt = ((t & 15) ^ sr) * 4; // swizzled LDS staging col

    const int bcol = blockIdx.y * 64;
    const float* Wb = W1 + (size_t)a * IN_DIM * HID_DIM + bcol;
    #define WLD(P,I) (*(const float4*)(Wb + (size_t)((P)*64 + sr + (I)*16) * HID_DIM + gc4))

    float4 wr0 = WLD(0,0), wr1 = WLD(0,1), wr2 = WLD(0,2), wr3 = WLD(0,3);

    #pragma unroll
    for (int s = 0; s < SB; ++s)
        sm[t * XPAD + s] = x[(size_t)s_sid[s] * IN_DIM + t];  // coalesced

    float acc[32];
    #pragma unroll
    for (int i = 0; i < 32; ++i) acc[i] = 0.f;

    for (int p = 0; p < IN_DIM / 64; ++p) {
        __syncthreads();                 // wS free; covers sm staging at p==0
        *(float4*)(&wS[(sr +  0) * 64 + slt]) = wr0;
        *(float4*)(&wS[(sr + 16) * 64 + slt]) = wr1;
        *(float4*)(&wS[(sr + 32) * 64 + slt]) = wr2;
        *(float4*)(&wS[(sr + 48) * 64 + slt]) = wr3;
        __syncthreads();
        if (p < 3) {                     // prefetch next tile -> regs
            wr0 = WLD(p+1,0); wr1 = WLD(p+1,1);
            wr2 = WLD(p+1,2); wr3 = WLD(p+1,3);
        }
        if (act) {
            #pragma unroll
            for (int i = 0; i < 8; ++i) {
                const int row = i * 8 + kq;
                const int rs  = row & 15;
                const float4 wv0 = *(const float4*)(&wS[row * 64 + ((2*cg    ^ rs) * 4)]);
                const float4 wv1 = *(const float4*)(&wS[row * 64 + (((2*cg+1) ^ rs) * 4)]);
                const float4 xv  = *(const float4*)(&sm[(p * 64 + row) * XPAD + w * 4]);
                const float wa[8] = {wv0.x, wv0.y, wv0.z, wv0.w,
                                     wv1.x, wv1.y, wv1.z, wv1.w};
                const float xa[4] = {xv.x, xv.y, xv.z, xv.w};
                #pragma unroll
                for (int cc = 0; cc < 8; ++cc)
                    #pragma unroll
                    for (int s = 0; s < 4; ++s)
                        acc[cc * 4 + s] = fmaf(wa[cc], xa[s], acc[cc * 4 + s]);
            }
        }
    }
    #undef WLD

    if (!act) return;
    #pragma unroll
    for (int i = 0; i < 32; ++i) {       // reduce over kq (lane bits 3-5)
        acc[i] += __shfl_xor(acc[i], 8);
        acc[i] += __shfl_xor(acc[i], 16);
        acc[i] += __shfl_xor(acc[i], 32);
    }
    if (kq != 0) return;

    const float4 bv0 = *(const float4*)(b1 + a * HID_DIM + bcol + cg * 8);
    const float4 bv1 = *(const float4*)(b1 + a * HID_DIM + bcol + cg * 8 + 4);
    const float ba[8] = {bv0.x, bv0.y, bv0.z, bv0.w,
                         bv1.x, bv1.y, bv1.z, bv1.w};
    float hv[32];
    #pragma unroll
    for (int cc = 0; cc < 8; ++cc)
        #pragma unroll
        for (int s = 0; s < 4; ++s)
            hv[cc * 4 + s] = fmaxf(acc[cc * 4 + s] + ba[cc], 0.f);

    #pragma unroll
    for (int s = 0; s < 4; ++s) {        // dup-slot writes identical
        float* hb = h_out + (size_t)s_sid[w * 4 + s] * HID_DIM + bcol + cg * 8;
        *(float4*)(hb)     = make_float4(hv[0*4+s], hv[1*4+s], hv[2*4+s], hv[3*4+s]);
        *(float4*)(hb + 4) = make_float4(hv[4*4+s], hv[5*4+s], hv[6*4+s], hv[7*4+s]);
    }

    float rp[32];                        // router partials [s][ch]
    #pragma unroll
    for (int i = 0; i < 32; ++i) rp[i] = 0.f;
    const float* rwa = rw + (size_t)a * HID_DIM * N_CHILD
                          + (size_t)(bcol + cg * 8) * N_CHILD;
    #pragma unroll
    for (int j = 0; j < 8; ++j)
        #pragma unroll
        for (int ch = 0; ch < 8; ++ch) {
            const float rv = rwa[j * N_CHILD + ch];
            #pragma unroll
            for (int s = 0; s < 4; ++s)
                rp[s * 8 + ch] = fmaf(hv[j * 4 + s], rv, rp[s * 8 + ch]);
        }
    #pragma unroll
    for (int i = 0; i < 32; ++i) {       // reduce over cg (lane bits 0-2)
        rp[i] += __shfl_xor(rp[i], 1);
        rp[i] += __shfl_xor(rp[i], 2);
        rp[i] += __shfl_xor(rp[i], 4);
    }
    if (cg == 0) {                       // direct partial store, no atomics
        float* rb = r_part + ((size_t)c * 8 + blockIdx.y) * 128 + w * 32;
        #pragma unroll
        for (int s4 = 0; s4 < 8; ++s4)
            *(float4*)(rb + s4 * 4) = make_float4(rp[s4*4+0], rp[s4*4+1],
                                                  rp[s4*4+2], rp[s4*4+3]);
    }
}

// ---------------- K2: OUT = H @ W2[a] + b2[a]; router final sum -------------
// grid (MAXCH, 4 tiles of 64 cols), 256 thr, 21.3 KB LDS. Full-K (8 passes)
// accumulation -> direct float4 stores, no atomics, no zeroing. Same 8x4
// blocking + swizzle. y==0 block also sums k1's router partials -> r_out.
extern "C" __global__ __launch_bounds__(256, 4)
void k2_mlp2(const float* __restrict__ h, const float* __restrict__ W2,
             const float* __restrict__ b2, const int* __restrict__ raw,
             const float* __restrict__ r_part,
             float* __restrict__ o_out, float* __restrict__ r_out)
{
    __shared__ float sm[64 * XPAD];      // 5 KB hT [k][s]
    __shared__ float wS[64 * 64];        // 16 KB W tile (swizzled)
    __shared__ int s_cnt[64], s_info[4], s_wsum[4], s_sid[SB];

    const int c = blockIdx.x;
    const int t = threadIdx.x;
    const int len = sort_chunk(raw, c, s_cnt, s_info, s_wsum, s_sid);
    if (len == 0) return;
    const int a = s_info[0];

    const int cg = t & 7;
    const int kq = (t >> 3) & 7;
    const int w  = t >> 6;
    const bool act = (w * 4) < len;
    const int sr  = t >> 4;
    const int gc4 = (t & 15) * 4;
    const int slt = ((t & 15) ^ sr) * 4;

    const int bcol = blockIdx.y * 64;
    const float* Wb = W2 + (size_t)a * HID_DIM * OUT_DIM + bcol;
    const int hrow = t & 63;
    const int hsb  = (t >> 6) * 4;
    #define WLD2(P,I) (*(const float4*)(Wb + (size_t)((P)*64 + sr + (I)*16) * OUT_DIM + gc4))
    #define HLD(P,J)  (h[(size_t)s_sid[hsb + (J)] * HID_DIM + (P)*64 + hrow])

    float4 wr0 = WLD2(0,0), wr1 = WLD2(0,1), wr2 = WLD2(0,2), wr3 = WLD2(0,3);
    float  hr0 = HLD(0,0),  hr1 = HLD(0,1),  hr2 = HLD(0,2),  hr3 = HLD(0,3);

    float acc[32];
    #pragma unroll
    for (int i = 0; i < 32; ++i) acc[i] = 0.f;

    for (int p = 0; p < HID_DIM / 64; ++p) {
        __syncthreads();
        sm[hrow * XPAD + hsb + 0] = hr0;
        sm[hrow * XPAD + hsb + 1] = hr1;
        sm[hrow * XPAD + hsb + 2] = hr2;
        sm[hrow * XPAD + hsb + 3] = hr3;
        *(float4*)(&wS[(sr +  0) * 64 + slt]) = wr0;
        *(float4*)(&wS[(sr + 16) * 64 + slt]) = wr1;
        *(float4*)(&wS[(sr + 32) * 64 + slt]) = wr2;
        *(float4*)(&wS[(sr + 48) * 64 + slt]) = wr3;
        __syncthreads();
        if (p < 7) {
            wr0 = WLD2(p+1,0); wr1 = WLD2(p+1,1);
            wr2 = WLD2(p+1,2); wr3 = WLD2(p+1,3);
            hr0 = HLD(p+1,0);  hr1 = HLD(p+1,1);
            hr2 = HLD(p+1,2);  hr3 = HLD(p+1,3);
        }
        if (act) {
            #pragma unroll
            for (int i = 0; i < 8; ++i) {
                const int row = i * 8 + kq;
                const int rs  = row & 15;
                const float4 wv0 = *(const float4*)(&wS[row * 64 + ((2*cg    ^ rs) * 4)]);
                const float4 wv1 = *(const float4*)(&wS[row * 64 + (((2*cg+1) ^ rs) * 4)]);
                const float4 xv  = *(const float4*)(&sm[row * XPAD + w * 4]);
                const float wa[8] = {wv0.x, wv0.y, wv0.z, wv0.w,
                                     wv1.x, wv1.y, wv1.z, wv1.w};
                const float xa[4] = {xv.x, xv.y, xv.z, xv.w};
                #pragma unroll
                for (int cc = 0; cc < 8; ++cc)
                    #pragma unroll
                    for (int s = 0; s < 4; ++s)
                        acc[cc * 4 + s] = fmaf(wa[cc], xa[s], acc[cc * 4 + s]);
            }
        }
    }
    #undef WLD2
    #undef HLD

    if (act) {
        #pragma unroll
        for (int i = 0; i < 32; ++i) {   // reduce over kq (lane bits 3-5)
            acc[i] += __shfl_xor(acc[i], 8);
            acc[i] += __shfl_xor(acc[i], 16);
            acc[i] += __shfl_xor(acc[i], 32);
        }
        if (kq == 0) {
            const float4 bv0 = *(const float4*)(b2 + a * OUT_DIM + bcol + cg * 8);
            const float4 bv1 = *(const float4*)(b2 + a * OUT_DIM + bcol + cg * 8 + 4);
            #pragma unroll
            for (int s = 0; s < 4; ++s) {
                const int g = w * 4 + s;
                if (g < len) {           // strict gating: one writer per row
                    float* op = o_out + (size_t)s_sid[g] * OUT_DIM + bcol + cg * 8;
                    *(float4*)(op)     = make_float4(acc[0*4+s] + bv0.x, acc[1*4+s] + bv0.y,
                                                     acc[2*4+s] + bv0.z, acc[3*4+s] + bv0.w);
                    *(float4*)(op + 4) = make_float4(acc[4*4+s] + bv1.x, acc[5*4+s] + bv1.y,
                                                     acc[6*4+s] + bv1.z, acc[7*4+s] + bv1.w);
                }
            }
        }
    }
    if (blockIdx.y == 0 && t < 128) {    // router final: sum 8 partials
        const int s = t >> 3;
        if (s < len) {
            float sum = 0.f;
            #pragma unroll
            for (int yy = 0; yy < 8; ++yy)
                sum += r_part[((size_t)c * 8 + yy) * 128 + t];
            r_out[(size_t)s_sid[s] * N_CHILD + (t & 7)] = sum;
        }
    }
}

extern "C" void kernel_launch(void* const* d_in, const int* in_sizes, int n_in,
                              void* d_out, int out_size, void* d_ws, size_t ws_size,
                              hipStream_t stream) {
    const float* x  = (const float*)d_in[0];
    const float* W1 = (const float*)d_in[1];
    const float* b1 = (const float*)d_in[2];
    const float* W2 = (const float*)d_in[3];
    const float* b2 = (const float*)d_in[4];
    const float* rw = (const float*)d_in[5];
    const int* raw  = (const int*)d_in[6];

    float* r_part = (float*)d_ws;        // [MAXCH][8][16][8] = 512 KB

    float* out   = (float*)d_out;
    float* h_out = out;                                   // [B, HID]
    float* o_out = h_out + (size_t)BATCH * HID_DIM;       // [B, OUT]
    float* r_out = o_out + (size_t)BATCH * OUT_DIM;       // [B, C]

    hipLaunchKernelGGL(k1_mlp1, dim3(MAXCH, 8), dim3(256), 0, stream,
                       x, W1, b1, rw, raw, h_out, r_part);
    hipLaunchKernelGGL(k2_mlp2, dim3(MAXCH, 4), dim3(256), 0, stream,
                       h_out, W2, b2, raw, r_part, o_out, r_out);
}

// Round 5
// 145.143 us; speedup vs baseline: 3.2887x; 1.0597x over previous
//
#include <hip/hip_runtime.h>

#define IN_DIM   256
#define HID_DIM  512
#define OUT_DIM  256
#define N_CHILD  8
#define BATCH    1024

#define SB    16   // samples per chunk
#define XPAD  20   // [k][s] LDS stride: 16B-aligned float4 groups, bank-spread
#define MAXCH 128  // sum ceil(n_a/16) <= (1024 + 64*15)/16 = 124 < 128

// ---------------- fused per-block chunk derivation --------------------------
// Every block recomputes the counting sort deterministically from raw ids:
// identical chunk->samples maps in all blocks, no inter-block traffic.
__device__ __forceinline__ int sort_chunk(const int* __restrict__ raw, const int c,
                                          int* s_cnt, int* s_info, int* s_wsum,
                                          int* s_sid)
{
    const int t = threadIdx.x;           // 256 threads
    const int lane = t & 63, w = t >> 6;
    if (t < 64) s_cnt[t] = 0;
    if (t == 0) { s_info[2] = 0; s_info[3] = 0; }
    __syncthreads();
    // int32 vs int64 agent_indices: odd 32-bit words of first 1024 ints
    if (raw[2 * t + 1] != 0 || raw[2 * (t + 256) + 1] != 0) s_info[3] = 1;
    __syncthreads();
    const int is32 = s_info[3];
    int myid[4];
    #pragma unroll
    for (int j = 0; j < 4; ++j) {
        const int i = t * 4 + j;
        const int v = (is32 ? raw[i] : raw[2 * i]) & 63;
        myid[j] = v;
        atomicAdd(&s_cnt[v], 1);
    }
    __syncthreads();
    if (t < 64) {                        // wave 0: chunk table prefix scan
        const int ca  = s_cnt[t];
        const int nch = (ca + SB - 1) / SB;
        int sn = nch;
        #pragma unroll
        for (int d = 1; d < 64; d <<= 1) {
            const int v = __shfl_up(sn, d);
            if (lane >= d) sn += v;
        }
        const int chb = sn - nch;        // first chunk of agent t
        if (c >= chb && c < chb + nch) { // exactly one agent claims chunk c
            s_info[0] = t;
            const int p = (c - chb) * SB;
            s_info[1] = p;
            s_info[2] = (ca - p < SB) ? (ca - p) : SB;
        }
    }
    __syncthreads();
    const int len = s_info[2];
    if (len == 0) return 0;              // c >= total chunks
    const int a = s_info[0], p = s_info[1];
    int m = 0;
    #pragma unroll
    for (int j = 0; j < 4; ++j) if (myid[j] == a) ++m;
    int inc = m;                         // inclusive wave scan of match counts
    #pragma unroll
    for (int d = 1; d < 64; d <<= 1) {
        const int v = __shfl_up(inc, d);
        if (lane >= d) inc += v;
    }
    if (lane == 63) s_wsum[w] = inc;
    __syncthreads();
    int base = inc - m;                  // exclusive rank base
    #pragma unroll
    for (int ww = 0; ww < 4; ++ww) if (ww < w) base += s_wsum[ww];
    #pragma unroll
    for (int j = 0; j < 4; ++j)
        if (myid[j] == a) {              // stable rank among agent's samples
            const int r = (base++) - p;
            if (r >= 0 && r < SB) s_sid[r] = t * 4 + j;
        }
    __syncthreads();
    if (t >= len && t < SB) s_sid[t] = s_sid[len - 1];   // pad = dup
    __syncthreads();
    return len;
}

// ---------------- K1: H = relu(X @ W1[a] + b1[a]); router partials -> ws ----
// grid (MAXCH, 8 tiles of 64 cols), 256 thr. LDS only 20.6 KB (xT) -> 7
// blk/CU. W is NOT staged in LDS: each lane streams its W fragments straight
// from global (4-wave redundancy absorbed by L1/L2; 64 MB L2-side ~2 us).
// => K-loop has ZERO barriers; 64 independent float4 loads give the compiler
// full ILP scheduling freedom (latency hidden by ILP + 28 waves/CU).
// Mapping: cg=t&15 (4 cols), kq=(t>>4)&3 (rows ≡ kq mod 4), w=t>>6 (4 smp).
extern "C" __global__ __launch_bounds__(256, 4)
void k1_mlp1(const float* __restrict__ x, const float* __restrict__ W1,
             const float* __restrict__ b1, const float* __restrict__ rw,
             const int* __restrict__ raw,
             float* __restrict__ h_out, float* __restrict__ r_part)
{
    __shared__ float xT[IN_DIM * XPAD];  // 20 KB, [k][s]
    __shared__ int s_cnt[64], s_info[4], s_wsum[4], s_sid[SB];

    const int c = blockIdx.x;
    const int t = threadIdx.x;
    const int len = sort_chunk(raw, c, s_cnt, s_info, s_wsum, s_sid);
    if (len == 0) return;
    const int a = s_info[0];
    const int bcol = blockIdx.y * 64;

    #pragma unroll
    for (int s = 0; s < SB; ++s)         // coalesced: 256 consecutive / s
        xT[t * XPAD + s] = x[(size_t)s_sid[s] * IN_DIM + t];
    __syncthreads();                     // the ONLY barrier after sort

    const int cg = t & 15;
    const int kq = (t >> 4) & 3;
    const int w  = t >> 6;
    if (w * 4 >= len) return;            // wave-uniform exit; no barriers left

    const float* Wb = W1 + (size_t)a * IN_DIM * HID_DIM + bcol + cg * 4;

    float acc[16];
    #pragma unroll
    for (int i = 0; i < 16; ++i) acc[i] = 0.f;

    #pragma unroll
    for (int i = 0; i < 64; ++i) {       // rows kq, kq+4, ..., kq+252
        const int row = i * 4 + kq;
        const float4 wv = *(const float4*)(Wb + (size_t)row * HID_DIM);
        const float4 xv = *(const float4*)(&xT[row * XPAD + w * 4]);
        const float wa[4] = {wv.x, wv.y, wv.z, wv.w};
        const float xa[4] = {xv.x, xv.y, xv.z, xv.w};
        #pragma unroll
        for (int cc = 0; cc < 4; ++cc)
            #pragma unroll
            for (int s = 0; s < 4; ++s)
                acc[cc * 4 + s] = fmaf(wa[cc], xa[s], acc[cc * 4 + s]);
    }

    #pragma unroll
    for (int i = 0; i < 16; ++i) {       // reduce over kq (lane bits 4-5)
        acc[i] += __shfl_xor(acc[i], 16);
        acc[i] += __shfl_xor(acc[i], 32);
    }
    if (kq != 0) return;                 // epilogue on kq==0 lanes only

    const float4 bv = *(const float4*)(b1 + a * HID_DIM + bcol + cg * 4);
    const float ba[4] = {bv.x, bv.y, bv.z, bv.w};
    float hv[16];
    #pragma unroll
    for (int cc = 0; cc < 4; ++cc)
        #pragma unroll
        for (int s = 0; s < 4; ++s)
            hv[cc * 4 + s] = fmaxf(acc[cc * 4 + s] + ba[cc], 0.f);

    #pragma unroll
    for (int s = 0; s < 4; ++s) {        // dup-slot writes identical
        float4 v = make_float4(hv[0 * 4 + s], hv[1 * 4 + s],
                               hv[2 * 4 + s], hv[3 * 4 + s]);
        *(float4*)(h_out + (size_t)s_sid[w * 4 + s] * HID_DIM + bcol + cg * 4) = v;
    }

    float rp[32];                        // router partials [s][ch]
    #pragma unroll
    for (int i = 0; i < 32; ++i) rp[i] = 0.f;
    const float* rwa = rw + (size_t)a * HID_DIM * N_CHILD
                          + (size_t)(bcol + cg * 4) * N_CHILD;
    #pragma unroll
    for (int j = 0; j < 4; ++j)
        #pragma unroll
        for (int ch = 0; ch < 8; ++ch) {
            const float rv = rwa[j * N_CHILD + ch];
            #pragma unroll
            for (int s = 0; s < 4; ++s)
                rp[s * 8 + ch] = fmaf(hv[j * 4 + s], rv, rp[s * 8 + ch]);
        }
    #pragma unroll
    for (int i = 0; i < 32; ++i) {       // reduce over cg (lane bits 0-3)
        rp[i] += __shfl_xor(rp[i], 1);
        rp[i] += __shfl_xor(rp[i], 2);
        rp[i] += __shfl_xor(rp[i], 4);
        rp[i] += __shfl_xor(rp[i], 8);
    }
    if (cg == 0) {                       // direct partial store, no atomics
        float* rb = r_part + ((size_t)c * 8 + blockIdx.y) * 128 + w * 32;
        #pragma unroll
        for (int s4 = 0; s4 < 8; ++s4)
            *(float4*)(rb + s4 * 4) = make_float4(rp[s4*4+0], rp[s4*4+1],
                                                  rp[s4*4+2], rp[s4*4+3]);
    }
}

// ---------------- K2: OUT = H @ W2[a] + b2[a]; router final sum -------------
// grid (MAXCH, 8 tiles of 32 cols) = 1024 blocks, 256 thr, 20.6 KB LDS.
// W2 streamed from global (no LDS tile). hT staged in two 256-row halves
// (2 barriers total). Full-K accumulation -> direct stores, no atomics.
// Mapping: cg=t&7 (4 cols), kq=(t>>3)&7 (rows ≡ kq mod 8), w=t>>6.
// y==0 block also sums k1's router partials -> r_out.
extern "C" __global__ __launch_bounds__(256, 4)
void k2_mlp2(const float* __restrict__ h, const float* __restrict__ W2,
             const float* __restrict__ b2, const int* __restrict__ raw,
             const float* __restrict__ r_part,
             float* __restrict__ o_out, float* __restrict__ r_out)
{
    __shared__ float hT[256 * XPAD];     // 20 KB, one K-half [k][s]
    __shared__ int s_cnt[64], s_info[4], s_wsum[4], s_sid[SB];

    const int c = blockIdx.x;
    const int t = threadIdx.x;
    const int len = sort_chunk(raw, c, s_cnt, s_info, s_wsum, s_sid);
    if (len == 0) return;
    const int a = s_info[0];
    const int bcol = blockIdx.y * 32;

    const int cg = t & 7;
    const int kq = (t >> 3) & 7;
    const int w  = t >> 6;
    const bool act = (w * 4) < len;
    const float* Wb = W2 + (size_t)a * HID_DIM * OUT_DIM + bcol + cg * 4;

    float acc[16];
    #pragma unroll
    for (int i = 0; i < 16; ++i) acc[i] = 0.f;

    #pragma unroll
    for (int half = 0; half < 2; ++half) {
        const int kb = half * 256;
        #pragma unroll
        for (int s = 0; s < SB; ++s)     // coalesced: 256 consecutive / s
            hT[t * XPAD + s] = h[(size_t)s_sid[s] * HID_DIM + kb + t];
        __syncthreads();
        if (act) {
            #pragma unroll
            for (int i = 0; i < 32; ++i) {   // rows ≡ kq mod 8 in this half
                const int row = i * 8 + kq;
                const float4 wv = *(const float4*)(Wb + (size_t)(kb + row) * OUT_DIM);
                const float4 xv = *(const float4*)(&hT[row * XPAD + w * 4]);
                const float wa[4] = {wv.x, wv.y, wv.z, wv.w};
                const float xa[4] = {xv.x, xv.y, xv.z, xv.w};
                #pragma unroll
                for (int cc = 0; cc < 4; ++cc)
                    #pragma unroll
                    for (int s = 0; s < 4; ++s)
                        acc[cc * 4 + s] = fmaf(wa[cc], xa[s], acc[cc * 4 + s]);
            }
        }
        if (half == 0) __syncthreads();  // hT reused; all waves participate
    }

    if (act) {
        #pragma unroll
        for (int i = 0; i < 16; ++i) {   // reduce over kq (lane bits 3-5)
            acc[i] += __shfl_xor(acc[i], 8);
            acc[i] += __shfl_xor(acc[i], 16);
            acc[i] += __shfl_xor(acc[i], 32);
        }
        if (kq == 0) {
            const float4 bv = *(const float4*)(b2 + a * OUT_DIM + bcol + cg * 4);
            #pragma unroll
            for (int s = 0; s < 4; ++s) {
                const int g = w * 4 + s;
                if (g < len) {           // strict gating: one writer per row
                    float4 v = make_float4(acc[0*4+s] + bv.x, acc[1*4+s] + bv.y,
                                           acc[2*4+s] + bv.z, acc[3*4+s] + bv.w);
                    *(float4*)(o_out + (size_t)s_sid[g] * OUT_DIM + bcol + cg * 4) = v;
                }
            }
        }
    }
    if (blockIdx.y == 0 && t < 128) {    // router final: sum 8 partials
        const int s = t >> 3;
        if (s < len) {
            float sum = 0.f;
            #pragma unroll
            for (int yy = 0; yy < 8; ++yy)
                sum += r_part[((size_t)c * 8 + yy) * 128 + t];
            r_out[(size_t)s_sid[s] * N_CHILD + (t & 7)] = sum;
        }
    }
}

extern "C" void kernel_launch(void* const* d_in, const int* in_sizes, int n_in,
                              void* d_out, int out_size, void* d_ws, size_t ws_size,
                              hipStream_t stream) {
    const float* x  = (const float*)d_in[0];
    const float* W1 = (const float*)d_in[1];
    const float* b1 = (const float*)d_in[2];
    const float* W2 = (const float*)d_in[3];
    const float* b2 = (const float*)d_in[4];
    const float* rw = (const float*)d_in[5];
    const int* raw  = (const int*)d_in[6];

    float* r_part = (float*)d_ws;        // [MAXCH][8][16][8] = 512 KB

    float* out   = (float*)d_out;
    float* h_out = out;                                   // [B, HID]
    float* o_out = h_out + (size_t)BATCH * HID_DIM;       // [B, OUT]
    float* r_out = o_out + (size_t)BATCH * OUT_DIM;       // [B, C]

    hipLaunchKernelGGL(k1_mlp1, dim3(MAXCH, 8), dim3(256), 0, stream,
                       x, W1, b1, rw, raw, h_out, r_part);
    hipLaunchKernelGGL(k2_mlp2, dim3(MAXCH, 8), dim3(256), 0, stream,
                       h_out, W2, b2, raw, r_part, o_out, r_out);
}

// Round 8
// 136.843 us; speedup vs baseline: 3.4882x; 1.0607x over previous
//
#include <hip/hip_runtime.h>

#define IN_DIM   256
#define HID_DIM  512
#define OUT_DIM  256
#define N_CHILD  8
#define BATCH    1024

#define SB    16   // samples per chunk
#define XPAD  20   // [k][s] LDS stride: 16B-aligned float4 groups, bank-spread
#define MAXCH 128  // sum ceil(n_a/16) <= (1024 + 64*15)/16 = 124 < 128

// ---------------- fused per-block chunk derivation --------------------------
// Every block recomputes the counting sort deterministically from raw ids:
// identical chunk->samples maps in all blocks, no inter-block traffic.
__device__ __forceinline__ int sort_chunk(const int* __restrict__ raw, const int c,
                                          int* s_cnt, int* s_info, int* s_wsum,
                                          int* s_sid)
{
    const int t = threadIdx.x;           // 256 threads
    const int lane = t & 63, w = t >> 6;
    if (t < 64) s_cnt[t] = 0;
    if (t == 0) { s_info[2] = 0; s_info[3] = 0; }
    __syncthreads();
    // int32 vs int64 agent_indices: odd 32-bit words of first 1024 ints
    if (raw[2 * t + 1] != 0 || raw[2 * (t + 256) + 1] != 0) s_info[3] = 1;
    __syncthreads();
    const int is32 = s_info[3];
    int myid[4];
    #pragma unroll
    for (int j = 0; j < 4; ++j) {
        const int i = t * 4 + j;
        const int v = (is32 ? raw[i] : raw[2 * i]) & 63;
        myid[j] = v;
        atomicAdd(&s_cnt[v], 1);
    }
    __syncthreads();
    if (t < 64) {                        // wave 0: chunk table prefix scan
        const int ca  = s_cnt[t];
        const int nch = (ca + SB - 1) / SB;
        int sn = nch;
        #pragma unroll
        for (int d = 1; d < 64; d <<= 1) {
            const int v = __shfl_up(sn, d);
            if (lane >= d) sn += v;
        }
        const int chb = sn - nch;        // first chunk of agent t
        if (c >= chb && c < chb + nch) { // exactly one agent claims chunk c
            s_info[0] = t;
            const int p = (c - chb) * SB;
            s_info[1] = p;
            s_info[2] = (ca - p < SB) ? (ca - p) : SB;
        }
    }
    __syncthreads();
    const int len = s_info[2];
    if (len == 0) return 0;              // c >= total chunks
    const int a = s_info[0], p = s_info[1];
    int m = 0;
    #pragma unroll
    for (int j = 0; j < 4; ++j) if (myid[j] == a) ++m;
    int inc = m;                         // inclusive wave scan of match counts
    #pragma unroll
    for (int d = 1; d < 64; d <<= 1) {
        const int v = __shfl_up(inc, d);
        if (lane >= d) inc += v;
    }
    if (lane == 63) s_wsum[w] = inc;
    __syncthreads();
    int base = inc - m;                  // exclusive rank base
    #pragma unroll
    for (int ww = 0; ww < 4; ++ww) if (ww < w) base += s_wsum[ww];
    #pragma unroll
    for (int j = 0; j < 4; ++j)
        if (myid[j] == a) {              // stable rank among agent's samples
            const int r = (base++) - p;
            if (r >= 0 && r < SB) s_sid[r] = t * 4 + j;
        }
    __syncthreads();
    if (t >= len && t < SB) s_sid[t] = s_sid[len - 1];   // pad = dup
    __syncthreads();
    return len;
}

// ---------------- K1: H = relu(X @ W1[a] + b1[a]); router partials -> ws ----
// grid (MAXCH, 8 tiles of 64 cols) = 1024 blocks, 256 thr, 37.2 KB LDS ->
// exactly 4 blk/CU, all co-resident, single round.
// W staged in LDS with DOUBLE-BUFFERED one-barrier-per-pass schedule:
//   pass p: issue loads(p+1) -> write regs(p) to buf[p&1] (vmcnt waits only
//   on the old loads; new ones stay in flight) -> ONE barrier -> compute.
// Write-after-read safe: reads of buf[b] in compute(p) precede (program
// order) the pass-p+1 barrier; writes to buf[b] at pass p+2 come after it.
// Mapping 4x4: cg=t&15 (4 cols), kq=(t>>4)&3, w=t>>6 (4 samples).
extern "C" __global__ __launch_bounds__(256, 4)
void k1_mlp1(const float* __restrict__ x, const float* __restrict__ W1,
             const float* __restrict__ b1, const float* __restrict__ rw,
             const int* __restrict__ raw,
             float* __restrict__ h_out, float* __restrict__ r_part)
{
    __shared__ float xT[IN_DIM * XPAD];  // 20 KB, [k][s], staged once
    __shared__ float wS[2][32 * 64];     // 2 x 8 KB W tile double-buffer
    __shared__ int s_cnt[64], s_info[4], s_wsum[4], s_sid[SB];

    const int c = blockIdx.x;
    const int t = threadIdx.x;
    const int len = sort_chunk(raw, c, s_cnt, s_info, s_wsum, s_sid);
    if (len == 0) return;                // block-uniform
    const int a = s_info[0];
    const int bcol = blockIdx.y * 64;

    const int cg = t & 15;
    const int kq = (t >> 4) & 3;
    const int w  = t >> 6;
    const bool act = (w * 4) < len;
    const int row0 = t >> 4;             // staging rows row0, row0+16 (0..31)
    const int sc4  = (t & 15) * 4;       // staging col

    const float* Wb = W1 + (size_t)a * IN_DIM * HID_DIM + bcol;
    #define WLD(P,I) (*(const float4*)(Wb + (size_t)((P)*32 + row0 + (I)*16) * HID_DIM + sc4))

    float4 ldA0 = WLD(0,0), ldA1 = WLD(0,1);   // tile 0 in flight

    #pragma unroll
    for (int s = 0; s < SB; ++s)         // coalesced per s (256 consecutive)
        xT[t * XPAD + s] = x[(size_t)s_sid[s] * IN_DIM + t];

    float acc[16];
    #pragma unroll
    for (int i = 0; i < 16; ++i) acc[i] = 0.f;

    for (int p = 0; p < 8; ++p) {        // 8 passes of 32 k-rows
        float4 ldB0 = ldA0, ldB1 = ldA1;
        if (p < 7) { ldB0 = WLD(p+1,0); ldB1 = WLD(p+1,1); }  // issue FIRST
        float* buf = wS[p & 1];
        *(float4*)(&buf[(row0 +  0) * 64 + sc4]) = ldA0;      // waits old only
        *(float4*)(&buf[(row0 + 16) * 64 + sc4]) = ldA1;
        __syncthreads();                 // ONE barrier per pass (uniform)
        if (act) {
            #pragma unroll
            for (int i = 0; i < 8; ++i) {
                const int row = i * 4 + kq;
                const float4 wv = *(const float4*)(&buf[row * 64 + cg * 4]);
                const float4 xv = *(const float4*)(&xT[(p * 32 + row) * XPAD + w * 4]);
                const float wa[4] = {wv.x, wv.y, wv.z, wv.w};
                const float xa[4] = {xv.x, xv.y, xv.z, xv.w};
                #pragma unroll
                for (int cc = 0; cc < 4; ++cc)
                    #pragma unroll
                    for (int s = 0; s < 4; ++s)
                        acc[cc * 4 + s] = fmaf(wa[cc], xa[s], acc[cc * 4 + s]);
            }
        }
        ldA0 = ldB0; ldA1 = ldB1;
    }
    #undef WLD

    if (!act) return;
    #pragma unroll
    for (int i = 0; i < 16; ++i) {       // reduce over kq (lane bits 4-5)
        acc[i] += __shfl_xor(acc[i], 16);
        acc[i] += __shfl_xor(acc[i], 32);
    }
    if (kq != 0) return;                 // epilogue on kq==0 lanes only

    const float4 bv = *(const float4*)(b1 + a * HID_DIM + bcol + cg * 4);
    const float ba[4] = {bv.x, bv.y, bv.z, bv.w};
    float hv[16];
    #pragma unroll
    for (int cc = 0; cc < 4; ++cc)
        #pragma unroll
        for (int s = 0; s < 4; ++s)
            hv[cc * 4 + s] = fmaxf(acc[cc * 4 + s] + ba[cc], 0.f);

    #pragma unroll
    for (int s = 0; s < 4; ++s) {        // dup-slot writes identical
        float4 v = make_float4(hv[0 * 4 + s], hv[1 * 4 + s],
                               hv[2 * 4 + s], hv[3 * 4 + s]);
        *(float4*)(h_out + (size_t)s_sid[w * 4 + s] * HID_DIM + bcol + cg * 4) = v;
    }

    float rp[32];                        // router partials [s][ch]
    #pragma unroll
    for (int i = 0; i < 32; ++i) rp[i] = 0.f;
    const float* rwa = rw + (size_t)a * HID_DIM * N_CHILD
                          + (size_t)(bcol + cg * 4) * N_CHILD;
    #pragma unroll
    for (int j = 0; j < 4; ++j)
        #pragma unroll
        for (int ch = 0; ch < 8; ++ch) {
            const float rv = rwa[j * N_CHILD + ch];
            #pragma unroll
            for (int s = 0; s < 4; ++s)
                rp[s * 8 + ch] = fmaf(hv[j * 4 + s], rv, rp[s * 8 + ch]);
        }
    #pragma unroll
    for (int i = 0; i < 32; ++i) {       // reduce over cg (lane bits 0-3)
        rp[i] += __shfl_xor(rp[i], 1);
        rp[i] += __shfl_xor(rp[i], 2);
        rp[i] += __shfl_xor(rp[i], 4);
        rp[i] += __shfl_xor(rp[i], 8);
    }
    if (cg == 0) {                       // direct partial store, no atomics
        float* rb = r_part + ((size_t)c * 8 + blockIdx.y) * 128 + w * 32;
        #pragma unroll
        for (int s4 = 0; s4 < 8; ++s4)
            *(float4*)(rb + s4 * 4) = make_float4(rp[s4*4+0], rp[s4*4+1],
                                                  rp[s4*4+2], rp[s4*4+3]);
    }
}

// ---------------- K2: OUT = H @ W2[a] + b2[a]; router final sum -------------
// grid (MAXCH, 8 tiles of 32 cols) = 1024 blocks, 256 thr, 27 KB LDS ->
// 5 blk/CU, all co-resident. Both hT and wS double-buffered; same
// one-barrier-per-pass schedule (8 passes of 64 k-rows, full K=512).
// Direct float4 stores, no atomics. Mapping: cg=t&7 (4 cols), kq=(t>>3)&7.
// y==0 block also sums k1's router partials -> r_out.
extern "C" __global__ __launch_bounds__(256, 4)
void k2_mlp2(const float* __restrict__ h, const float* __restrict__ W2,
             const float* __restrict__ b2, const int* __restrict__ raw,
             const float* __restrict__ r_part,
             float* __restrict__ o_out, float* __restrict__ r_out)
{
    __shared__ float hT[2][64 * XPAD];   // 2 x 5 KB h tile double-buffer
    __shared__ float wS[2][64 * 32];     // 2 x 8 KB W tile double-buffer
    __shared__ int s_cnt[64], s_info[4], s_wsum[4], s_sid[SB];

    const int c = blockIdx.x;
    const int t = threadIdx.x;
    const int len = sort_chunk(raw, c, s_cnt, s_info, s_wsum, s_sid);
    if (len == 0) return;                // block-uniform
    const int a = s_info[0];
    const int bcol = blockIdx.y * 32;

    const int cg = t & 7;
    const int kq = (t >> 3) & 7;
    const int w  = t >> 6;
    const bool act = (w * 4) < len;
    const int row0 = t >> 3;             // W staging rows row0, row0+32 (0..63)
    const int sc4  = (t & 7) * 4;        // W staging col
    const int hrow = t & 63;             // h staging: 64 consecutive k
    const int hsb  = (t >> 6) * 4;       // 4 samples per wave-group

    const float* Wb = W2 + (size_t)a * HID_DIM * OUT_DIM + bcol;
    #define WLD2(P,I) (*(const float4*)(Wb + (size_t)((P)*64 + row0 + (I)*32) * OUT_DIM + sc4))
    #define HLD(P,J)  (h[(size_t)s_sid[hsb + (J)] * HID_DIM + (P)*64 + hrow])

    float4 wA0 = WLD2(0,0), wA1 = WLD2(0,1);
    float  hA0 = HLD(0,0),  hA1 = HLD(0,1),  hA2 = HLD(0,2),  hA3 = HLD(0,3);

    float acc[16];
    #pragma unroll
    for (int i = 0; i < 16; ++i) acc[i] = 0.f;

    for (int p = 0; p < 8; ++p) {        // 8 passes of 64 k-rows
        float4 wB0 = wA0, wB1 = wA1;
        float  hB0 = hA0, hB1 = hA1, hB2 = hA2, hB3 = hA3;
        if (p < 7) {                     // issue next-tile loads FIRST
            wB0 = WLD2(p+1,0); wB1 = WLD2(p+1,1);
            hB0 = HLD(p+1,0);  hB1 = HLD(p+1,1);
            hB2 = HLD(p+1,2);  hB3 = HLD(p+1,3);
        }
        const int b = p & 1;
        hT[b][hrow * XPAD + hsb + 0] = hA0;      // waits only on old loads
        hT[b][hrow * XPAD + hsb + 1] = hA1;
        hT[b][hrow * XPAD + hsb + 2] = hA2;
        hT[b][hrow * XPAD + hsb + 3] = hA3;
        *(float4*)(&wS[b][(row0 +  0) * 32 + sc4]) = wA0;
        *(float4*)(&wS[b][(row0 + 32) * 32 + sc4]) = wA1;
        __syncthreads();                 // ONE barrier per pass (uniform)
        if (act) {
            #pragma unroll
            for (int i = 0; i < 8; ++i) {
                const int row = i * 8 + kq;
                const float4 wv = *(const float4*)(&wS[b][row * 32 + cg * 4]);
                const float4 xv = *(const float4*)(&hT[b][row * XPAD + w * 4]);
                const float wa[4] = {wv.x, wv.y, wv.z, wv.w};
                const float xa[4] = {xv.x, xv.y, xv.z, xv.w};
                #pragma unroll
                for (int cc = 0; cc < 4; ++cc)
                    #pragma unroll
                    for (int s = 0; s < 4; ++s)
                        acc[cc * 4 + s] = fmaf(wa[cc], xa[s], acc[cc * 4 + s]);
            }
        }
        wA0 = wB0; wA1 = wB1;
        hA0 = hB0; hA1 = hB1; hA2 = hB2; hA3 = hB3;
    }
    #undef WLD2
    #undef HLD

    if (act) {
        #pragma unroll
        for (int i = 0; i < 16; ++i) {   // reduce over kq (lane bits 3-5)
            acc[i] += __shfl_xor(acc[i], 8);
            acc[i] += __shfl_xor(acc[i], 16);
            acc[i] += __shfl_xor(acc[i], 32);
        }
        if (kq == 0) {
            const float4 bv = *(const float4*)(b2 + a * OUT_DIM + bcol + cg * 4);
            #pragma unroll
            for (int s = 0; s < 4; ++s) {
                const int g = w * 4 + s;
                if (g < len) {           // strict gating: one writer per row
                    float4 v = make_float4(acc[0*4+s] + bv.x, acc[1*4+s] + bv.y,
                                           acc[2*4+s] + bv.z, acc[3*4+s] + bv.w);
                    *(float4*)(o_out + (size_t)s_sid[g] * OUT_DIM + bcol + cg * 4) = v;
                }
            }
        }
    }
    if (blockIdx.y == 0 && t < 128) {    // router final: sum 8 partials
        const int s = t >> 3;
        if (s < len) {
            float sum = 0.f;
            #pragma unroll
            for (int yy = 0; yy < 8; ++yy)
                sum += r_part[((size_t)c * 8 + yy) * 128 + t];
            r_out[(size_t)s_sid[s] * N_CHILD + (t & 7)] = sum;
        }
    }
}

extern "C" void kernel_launch(void* const* d_in, const int* in_sizes, int n_in,
                              void* d_out, int out_size, void* d_ws, size_t ws_size,
                              hipStream_t stream) {
    const float* x  = (const float*)d_in[0];
    const float* W1 = (const float*)d_in[1];
    const float* b1 = (const float*)d_in[2];
    const float* W2 = (const float*)d_in[3];
    const float* b2 = (const float*)d_in[4];
    const float* rw = (const float*)d_in[5];
    const int* raw  = (const int*)d_in[6];

    float* r_part = (float*)d_ws;        // [MAXCH][8][16][8] = 512 KB

    float* out   = (float*)d_out;
    float* h_out = out;                                   // [B, HID]
    float* o_out = h_out + (size_t)BATCH * HID_DIM;       // [B, OUT]
    float* r_out = o_out + (size_t)BATCH * OUT_DIM;       // [B, C]

    hipLaunchKernelGGL(k1_mlp1, dim3(MAXCH, 8), dim3(256), 0, stream,
                       x, W1, b1, rw, raw, h_out, r_part);
    hipLaunchKernelGGL(k2_mlp2, dim3(MAXCH, 8), dim3(256), 0, stream,
                       h_out, W2, b2, raw, r_part, o_out, r_out);
}

// Round 9
// 128.798 us; speedup vs baseline: 3.7061x; 1.0625x over previous
//
#include <hip/hip_runtime.h>

#define IN_DIM   256
#define HID_DIM  512
#define OUT_DIM  256
#define N_CHILD  8
#define BATCH    1024

#define SB    16   // samples per chunk
#define XPAD  20   // [k][s] LDS stride: 16B-aligned float4 groups, bank-spread
#define MAXCH 128  // sum ceil(n_a/16) <= (1024 + 64*15)/16 = 124 < 128

// ---------------- fused per-block chunk derivation (replaces prep kernel) ---
// Every block recomputes the counting sort deterministically from raw ids:
// histogram via shared atomics (order-independent counts), chunk table via
// wave-0 prefix scan over ceil(cnt/16), stable sample ranks via 256-thread
// prefix scan of per-thread match counts (thread order = index order).
// All blocks derive IDENTICAL chunk->samples maps: no inter-block traffic.
__device__ __forceinline__ int sort_chunk(const int* __restrict__ raw, const int c,
                                          int* s_cnt, int* s_info, int* s_wsum,
                                          int* s_sid)
{
    const int t = threadIdx.x;           // 256 threads
    const int lane = t & 63, w = t >> 6;
    if (t < 64) s_cnt[t] = 0;
    if (t == 0) { s_info[2] = 0; s_info[3] = 0; }
    __syncthreads();
    // int32 vs int64 agent_indices: odd 32-bit words of first 1024 ints
    if (raw[2 * t + 1] != 0 || raw[2 * (t + 256) + 1] != 0) s_info[3] = 1;
    __syncthreads();
    const int is32 = s_info[3];
    int myid[4];
    #pragma unroll
    for (int j = 0; j < 4; ++j) {
        const int i = t * 4 + j;
        const int v = (is32 ? raw[i] : raw[2 * i]) & 63;
        myid[j] = v;
        atomicAdd(&s_cnt[v], 1);
    }
    __syncthreads();
    if (t < 64) {                        // wave 0: chunk table prefix scan
        const int ca  = s_cnt[t];
        const int nch = (ca + SB - 1) / SB;
        int sn = nch;
        #pragma unroll
        for (int d = 1; d < 64; d <<= 1) {
            const int v = __shfl_up(sn, d);
            if (lane >= d) sn += v;
        }
        const int chb = sn - nch;        // first chunk of agent t
        if (c >= chb && c < chb + nch) { // exactly one agent claims chunk c
            s_info[0] = t;
            const int p = (c - chb) * SB;
            s_info[1] = p;
            s_info[2] = (ca - p < SB) ? (ca - p) : SB;
        }
    }
    __syncthreads();
    const int len = s_info[2];
    if (len == 0) return 0;              // c >= total chunks
    const int a = s_info[0], p = s_info[1];
    int m = 0;
    #pragma unroll
    for (int j = 0; j < 4; ++j) if (myid[j] == a) ++m;
    int inc = m;                         // inclusive wave scan of match counts
    #pragma unroll
    for (int d = 1; d < 64; d <<= 1) {
        const int v = __shfl_up(inc, d);
        if (lane >= d) inc += v;
    }
    if (lane == 63) s_wsum[w] = inc;
    __syncthreads();
    int base = inc - m;                  // exclusive rank base
    #pragma unroll
    for (int ww = 0; ww < 4; ++ww) if (ww < w) base += s_wsum[ww];
    #pragma unroll
    for (int j = 0; j < 4; ++j)
        if (myid[j] == a) {              // stable rank among agent's samples
            const int r = (base++) - p;
            if (r >= 0 && r < SB) s_sid[r] = t * 4 + j;
        }
    __syncthreads();
    if (t >= len && t < SB) s_sid[t] = s_sid[len - 1];   // pad = dup
    __syncthreads();
    return len;
}

// ---------------- K1: H = relu(X @ W1[a] + b1[a]); router partials -> ws ----
// grid (MAXCH, 8 tiles of 64 cols), 256 thr. LDS 36.4 KB -> 4 blk/CU, all
// 1024 blocks co-resident. Register-prefetched single-LDS-buffer staging.
// Router: per-(chunk,y) partials stored (no atomics, no zeroing); k2 sums.
extern "C" __global__ __launch_bounds__(256)
void k1_mlp1(const float* __restrict__ x, const float* __restrict__ W1,
             const float* __restrict__ b1, const float* __restrict__ rw,
             const int* __restrict__ raw,
             float* __restrict__ h_out, float* __restrict__ r_part)
{
    __shared__ float xT[IN_DIM * XPAD];  // 20 KB, [k][s]
    __shared__ float wS[64 * 64];        // 16 KB W tile
    __shared__ int s_cnt[64], s_info[4], s_wsum[4], s_sid[SB];

    const int chunk = blockIdx.x;
    const int t = threadIdx.x;
    const int len = sort_chunk(raw, chunk, s_cnt, s_info, s_wsum, s_sid);
    if (len == 0) return;
    const int a    = s_info[0];
    const int bcol = blockIdx.y * 64;

    const float* Wb = W1 + (size_t)a * IN_DIM * HID_DIM + bcol;
    const int sr  = t >> 4;
    const int sc4 = (t & 15) * 4;
    #define WLD(P,I) (*(const float4*)(Wb + (size_t)((P)*64 + sr + (I)*16) * HID_DIM + sc4))

    float4 wr0 = WLD(0,0), wr1 = WLD(0,1), wr2 = WLD(0,2), wr3 = WLD(0,3);

    #pragma unroll
    for (int s = 0; s < SB; ++s)
        xT[t * XPAD + s] = x[(size_t)s_sid[s] * IN_DIM + t];     // coalesced

    const int cg = t & 15;
    const int kq = (t >> 4) & 3;
    const int w  = t >> 6;
    const bool act = (w * 4) < len;

    float acc[16];
    #pragma unroll
    for (int i = 0; i < 16; ++i) acc[i] = 0.f;

    for (int p = 0; p < IN_DIM / 64; ++p) {
        __syncthreads();                 // wS free; covers xT staging at p==0
        *(float4*)(&wS[(sr +  0) * 64 + sc4]) = wr0;
        *(float4*)(&wS[(sr + 16) * 64 + sc4]) = wr1;
        *(float4*)(&wS[(sr + 32) * 64 + sc4]) = wr2;
        *(float4*)(&wS[(sr + 48) * 64 + sc4]) = wr3;
        __syncthreads();
        if (p < 3) {
            wr0 = WLD(p+1,0); wr1 = WLD(p+1,1);
            wr2 = WLD(p+1,2); wr3 = WLD(p+1,3);
        }
        if (act) {
            #pragma unroll
            for (int i = 0; i < 16; ++i) {
                const int row = i * 4 + kq;
                const float4 wv = *(const float4*)(&wS[row * 64 + cg * 4]);
                const float4 xv = *(const float4*)(&xT[(p * 64 + row) * XPAD + w * 4]);
                const float wa[4] = {wv.x, wv.y, wv.z, wv.w};
                const float xa[4] = {xv.x, xv.y, xv.z, xv.w};
                #pragma unroll
                for (int c = 0; c < 4; ++c)
                    #pragma unroll
                    for (int s = 0; s < 4; ++s)
                        acc[c * 4 + s] = fmaf(wa[c], xa[s], acc[c * 4 + s]);
            }
        }
    }
    #undef WLD

    if (!act) return;
    #pragma unroll
    for (int i = 0; i < 16; ++i) {       // reduce over kq (lane bits 4-5)
        acc[i] += __shfl_xor(acc[i], 16);
        acc[i] += __shfl_xor(acc[i], 32);
    }
    if (kq != 0) return;

    const float4 bv = *(const float4*)(b1 + a * HID_DIM + bcol + cg * 4);
    const float ba[4] = {bv.x, bv.y, bv.z, bv.w};
    float hv[16];
    #pragma unroll
    for (int c = 0; c < 4; ++c)
        #pragma unroll
        for (int s = 0; s < 4; ++s)
            hv[c * 4 + s] = fmaxf(acc[c * 4 + s] + ba[c], 0.f);

    #pragma unroll
    for (int s = 0; s < 4; ++s) {        // dup-slot writes identical
        float4 v = make_float4(hv[0 * 4 + s], hv[1 * 4 + s],
                               hv[2 * 4 + s], hv[3 * 4 + s]);
        *(float4*)(h_out + (size_t)s_sid[w * 4 + s] * HID_DIM + bcol + cg * 4) = v;
    }

    float rp[32];                        // router partials [s][ch]
    #pragma unroll
    for (int i = 0; i < 32; ++i) rp[i] = 0.f;
    const float* rwa = rw + (size_t)a * HID_DIM * N_CHILD
                          + (size_t)(bcol + cg * 4) * N_CHILD;
    #pragma unroll
    for (int j = 0; j < 4; ++j)
        #pragma unroll
        for (int ch = 0; ch < 8; ++ch) {
            const float rv = rwa[j * N_CHILD + ch];
            #pragma unroll
            for (int s = 0; s < 4; ++s)
                rp[s * 8 + ch] = fmaf(hv[j * 4 + s], rv, rp[s * 8 + ch]);
        }
    #pragma unroll
    for (int i = 0; i < 32; ++i) {       // reduce over cg (lane bits 0-3)
        rp[i] += __shfl_xor(rp[i], 1);
        rp[i] += __shfl_xor(rp[i], 2);
        rp[i] += __shfl_xor(rp[i], 4);
        rp[i] += __shfl_xor(rp[i], 8);
    }
    if (cg == 0) {                       // direct partial store, no atomics
        float* rb = r_part + ((size_t)chunk * 8 + blockIdx.y) * 128 + w * 32;
        #pragma unroll
        for (int s4 = 0; s4 < 8; ++s4)
            *(float4*)(rb + s4 * 4) = make_float4(rp[s4*4+0], rp[s4*4+1],
                                                  rp[s4*4+2], rp[s4*4+3]);
    }
}

// ---------------- K2: OUT = H @ W2[a] + b2[a]; router final sum -------------
// grid (MAXCH, 8 tiles of 32 cols), 256 thr. LDS 13.6 KB -> 8 blk/CU (wave
// cap), 1024 blocks. Full-K accumulation, direct float4 stores (no atomics).
// 8-way K-split lanes: cg=t&7 (4 cols), kq=(t>>3)&7.
// y==0 block also sums k1's router partials -> r_out (no zeroing needed).
extern "C" __global__ __launch_bounds__(256)
void k2_mlp2(const float* __restrict__ h, const float* __restrict__ W2,
             const float* __restrict__ b2, const int* __restrict__ raw,
             const float* __restrict__ r_part,
             float* __restrict__ o_out, float* __restrict__ r_out)
{
    __shared__ float hT[64 * XPAD];      // 5 KB per-pass h tile
    __shared__ float wS[64 * 32];        // 8 KB per-pass W tile
    __shared__ int s_cnt[64], s_info[4], s_wsum[4], s_sid[SB];

    const int chunk = blockIdx.x;
    const int t = threadIdx.x;
    const int len = sort_chunk(raw, chunk, s_cnt, s_info, s_wsum, s_sid);
    if (len == 0) return;
    const int a    = s_info[0];
    const int bcol = blockIdx.y * 32;

    const float* Wb = W2 + (size_t)a * HID_DIM * OUT_DIM + bcol;
    const int r2   = t >> 3;             // staging row 0..31
    const int c4   = (t & 7) * 4;        // staging col
    const int hrow = t & 63;
    const int hsb  = (t >> 6) * 4;
    #define WLD2(P,I) (*(const float4*)(Wb + (size_t)((P)*64 + r2 + (I)*32) * OUT_DIM + c4))
    #define HLD(P,J)  (h[(size_t)s_sid[hsb + (J)] * HID_DIM + (P)*64 + hrow])

    float4 wr0 = WLD2(0,0), wr1 = WLD2(0,1);
    float  hr0 = HLD(0,0), hr1 = HLD(0,1), hr2 = HLD(0,2), hr3 = HLD(0,3);

    const int cg = t & 7;
    const int kq = (t >> 3) & 7;
    const int w  = t >> 6;
    const bool act = (w * 4) < len;

    float acc[16];
    #pragma unroll
    for (int i = 0; i < 16; ++i) acc[i] = 0.f;

    for (int p = 0; p < HID_DIM / 64; ++p) {
        __syncthreads();
        hT[hrow * XPAD + hsb + 0] = hr0;
        hT[hrow * XPAD + hsb + 1] = hr1;
        hT[hrow * XPAD + hsb + 2] = hr2;
        hT[hrow * XPAD + hsb + 3] = hr3;
        *(float4*)(&wS[(r2 +  0) * 32 + c4]) = wr0;
        *(float4*)(&wS[(r2 + 32) * 32 + c4]) = wr1;
        __syncthreads();
        if (p < 7) {
            wr0 = WLD2(p+1,0); wr1 = WLD2(p+1,1);
            hr0 = HLD(p+1,0);  hr1 = HLD(p+1,1);
            hr2 = HLD(p+1,2);  hr3 = HLD(p+1,3);
        }
        if (act) {
            #pragma unroll
            for (int i = 0; i < 8; ++i) {
                const int row = i * 8 + kq;  // kq-spread rows
                const float4 wv = *(const float4*)(&wS[row * 32 + cg * 4]);
                const float4 xv = *(const float4*)(&hT[row * XPAD + w * 4]);
                const float wa[4] = {wv.x, wv.y, wv.z, wv.w};
                const float xa[4] = {xv.x, xv.y, xv.z, xv.w};
                #pragma unroll
                for (int c = 0; c < 4; ++c)
                    #pragma unroll
                    for (int s = 0; s < 4; ++s)
                        acc[c * 4 + s] = fmaf(wa[c], xa[s], acc[c * 4 + s]);
            }
        }
    }
    #undef WLD2
    #undef HLD

    #pragma unroll
    for (int i = 0; i < 16; ++i) {       // reduce over kq (lane bits 3-5)
        acc[i] += __shfl_xor(acc[i], 8);
        acc[i] += __shfl_xor(acc[i], 16);
        acc[i] += __shfl_xor(acc[i], 32);
    }
    if (act && kq == 0) {
        const float4 bv = *(const float4*)(b2 + a * OUT_DIM + bcol + cg * 4);
        #pragma unroll
        for (int s = 0; s < 4; ++s) {
            const int g = w * 4 + s;
            if (g < len) {               // strict gating: one writer per row
                float4 v = make_float4(acc[0 * 4 + s] + bv.x,
                                       acc[1 * 4 + s] + bv.y,
                                       acc[2 * 4 + s] + bv.z,
                                       acc[3 * 4 + s] + bv.w);
                *(float4*)(o_out + (size_t)s_sid[g] * OUT_DIM + bcol + cg * 4) = v;
            }
        }
    }
    if (blockIdx.y == 0 && t < 128) {    // router final: sum 8 partials
        const int s = t >> 3;
        if (s < len) {
            float sum = 0.f;
            #pragma unroll
            for (int yy = 0; yy < 8; ++yy)
                sum += r_part[((size_t)chunk * 8 + yy) * 128 + t];
            r_out[(size_t)s_sid[s] * N_CHILD + (t & 7)] = sum;
        }
    }
}

extern "C" void kernel_launch(void* const* d_in, const int* in_sizes, int n_in,
                              void* d_out, int out_size, void* d_ws, size_t ws_size,
                              hipStream_t stream) {
    const float* x  = (const float*)d_in[0];
    const float* W1 = (const float*)d_in[1];
    const float* b1 = (const float*)d_in[2];
    const float* W2 = (const float*)d_in[3];
    const float* b2 = (const float*)d_in[4];
    const float* rw = (const float*)d_in[5];
    const int* raw  = (const int*)d_in[6];

    float* r_part = (float*)d_ws;        // [MAXCH][8][16][8] = 512 KB

    float* out   = (float*)d_out;
    float* h_out = out;                                   // [B, HID]
    float* o_out = h_out + (size_t)BATCH * HID_DIM;       // [B, OUT]
    float* r_out = o_out + (size_t)BATCH * OUT_DIM;       // [B, C]

    hipLaunchKernelGGL(k1_mlp1, dim3(MAXCH, 8), dim3(256), 0, stream,
                       x, W1, b1, rw, raw, h_out, r_part);
    hipLaunchKernelGGL(k2_mlp2, dim3(MAXCH, 8), dim3(256), 0, stream,
                       h_out, W2, b2, raw, r_part, o_out, r_out);
}

// Round 10
// 128.097 us; speedup vs baseline: 3.7264x; 1.0055x over previous
//
#include <hip/hip_runtime.h>

#define IN_DIM   256
#define HID_DIM  512
#define OUT_DIM  256
#define N_CHILD  8
#define BATCH    1024

#define SB    32   // samples per chunk (2x r9: halves W-staging per sample)
#define XS    36   // [k][s] LDS stride: 32+4, float4-aligned, bank-spread
#define MAXCH 96   // sum ceil(n_a/32) <= (1024 + 64*31)/32 = 94 < 96

// ---------------- fused per-block chunk derivation --------------------------
// Every block recomputes the counting sort deterministically from raw ids:
// identical chunk->samples maps in all blocks, no inter-block traffic.
__device__ __forceinline__ int sort_chunk(const int* __restrict__ raw, const int c,
                                          int* s_cnt, int* s_info, int* s_wsum,
                                          int* s_sid)
{
    const int t = threadIdx.x;           // 256 threads
    const int lane = t & 63, w = t >> 6;
    if (t < 64) s_cnt[t] = 0;
    if (t == 0) { s_info[2] = 0; s_info[3] = 0; }
    __syncthreads();
    // int32 vs int64 agent_indices: odd 32-bit words of first 1024 ints
    if (raw[2 * t + 1] != 0 || raw[2 * (t + 256) + 1] != 0) s_info[3] = 1;
    __syncthreads();
    const int is32 = s_info[3];
    int myid[4];
    #pragma unroll
    for (int j = 0; j < 4; ++j) {
        const int i = t * 4 + j;
        const int v = (is32 ? raw[i] : raw[2 * i]) & 63;
        myid[j] = v;
        atomicAdd(&s_cnt[v], 1);
    }
    __syncthreads();
    if (t < 64) {                        // wave 0: chunk table prefix scan
        const int ca  = s_cnt[t];
        const int nch = (ca + SB - 1) / SB;
        int sn = nch;
        #pragma unroll
        for (int d = 1; d < 64; d <<= 1) {
            const int v = __shfl_up(sn, d);
            if (lane >= d) sn += v;
        }
        const int chb = sn - nch;        // first chunk of agent t
        if (c >= chb && c < chb + nch) { // exactly one agent claims chunk c
            s_info[0] = t;
            const int p = (c - chb) * SB;
            s_info[1] = p;
            s_info[2] = (ca - p < SB) ? (ca - p) : SB;
        }
    }
    __syncthreads();
    const int len = s_info[2];
    if (len == 0) return 0;              // c >= total chunks
    const int a = s_info[0], p = s_info[1];
    int m = 0;
    #pragma unroll
    for (int j = 0; j < 4; ++j) if (myid[j] == a) ++m;
    int inc = m;                         // inclusive wave scan of match counts
    #pragma unroll
    for (int d = 1; d < 64; d <<= 1) {
        const int v = __shfl_up(inc, d);
        if (lane >= d) inc += v;
    }
    if (lane == 63) s_wsum[w] = inc;
    __syncthreads();
    int base = inc - m;                  // exclusive rank base
    #pragma unroll
    for (int ww = 0; ww < 4; ++ww) if (ww < w) base += s_wsum[ww];
    #pragma unroll
    for (int j = 0; j < 4; ++j)
        if (myid[j] == a) {              // stable rank among agent's samples
            const int r = (base++) - p;
            if (r >= 0 && r < SB) s_sid[r] = t * 4 + j;
        }
    __syncthreads();
    if (t >= len && t < SB) s_sid[t] = s_sid[len - 1];   // pad = dup
    __syncthreads();
    return len;
}

// ---------------- K1: H = relu(X @ W1[a] + b1[a]) ---------------------------
// grid (MAXCH, 8 tiles of 64 cols), 256 thr, 35.2 KB LDS -> 4 blk/CU.
// SB=32: one 16 KB W tile feeds 32 samples (W staging per sample halved).
// xT holds ONE K-half (128 rows); half 1 is prefetched into 16 regs during
// pass 1 and restaged at pass 2 (loads in flight across the barrier).
// Mapping 4x8: cg=t&15 (4 cols), kq=(t>>4)&3 (K-split), w=t>>6 (8 samples).
extern "C" __global__ __launch_bounds__(256)
void k1_mlp1(const float* __restrict__ x, const float* __restrict__ W1,
             const float* __restrict__ b1, const int* __restrict__ raw,
             float* __restrict__ h_out)
{
    __shared__ float xT[128 * XS];       // 18 KB, one K-half [k][s]
    __shared__ float wS[64 * 64];        // 16 KB W tile
    __shared__ int s_cnt[64], s_info[4], s_wsum[4], s_sid[SB];

    const int c = blockIdx.x;
    const int t = threadIdx.x;
    const int len = sort_chunk(raw, c, s_cnt, s_info, s_wsum, s_sid);
    if (len == 0) return;                // block-uniform
    const int a = s_info[0];
    const int bcol = blockIdx.y * 64;

    const float* Wb = W1 + (size_t)a * IN_DIM * HID_DIM + bcol;
    const int sr  = t >> 4;              // W staging rows sr,+16,+32,+48
    const int sc4 = (t & 15) * 4;
    #define WLD(P,I) (*(const float4*)(Wb + (size_t)((P)*64 + sr + (I)*16) * HID_DIM + sc4))

    float4 wr0 = WLD(0,0), wr1 = WLD(0,1), wr2 = WLD(0,2), wr3 = WLD(0,3);

    const int xrow = t & 127;            // x staging row within K-half
    const int xsg  = (t >> 7) * 16;      // sample group 0 or 16
    #pragma unroll
    for (int j = 0; j < 16; ++j)         // stage K-half 0 (coalesced per j)
        xT[xrow * XS + xsg + j] = x[(size_t)s_sid[xsg + j] * IN_DIM + xrow];

    const int cg = t & 15;
    const int kq = (t >> 4) & 3;
    const int w  = t >> 6;
    const bool act = (w * 8) < len;

    float acc[32];
    #pragma unroll
    for (int i = 0; i < 32; ++i) acc[i] = 0.f;
    float xh[16];

    for (int p = 0; p < 4; ++p) {        // 4 passes of 64 k-rows
        __syncthreads();                 // wS free; pass<=1 xT reads done @p==2
        if (p == 2) {
            #pragma unroll
            for (int j = 0; j < 16; ++j) // restage K-half 1 from prefetch regs
                xT[xrow * XS + xsg + j] = xh[j];
        }
        *(float4*)(&wS[(sr +  0) * 64 + sc4]) = wr0;
        *(float4*)(&wS[(sr + 16) * 64 + sc4]) = wr1;
        *(float4*)(&wS[(sr + 32) * 64 + sc4]) = wr2;
        *(float4*)(&wS[(sr + 48) * 64 + sc4]) = wr3;
        __syncthreads();
        if (p == 1) {                    // prefetch x K-half 1 (in flight
            #pragma unroll               //  across the p==2 barrier)
            for (int j = 0; j < 16; ++j)
                xh[j] = x[(size_t)s_sid[xsg + j] * IN_DIM + 128 + xrow];
        }
        if (p < 3) {                     // prefetch next W tile -> regs
            wr0 = WLD(p+1,0); wr1 = WLD(p+1,1);
            wr2 = WLD(p+1,2); wr3 = WLD(p+1,3);
        }
        if (act) {
            #pragma unroll
            for (int i = 0; i < 16; ++i) {
                const int row = i * 4 + kq;
                const int lr  = (p & 1) * 64 + row;   // row within xT half
                const float4 wv  = *(const float4*)(&wS[row * 64 + cg * 4]);
                const float4 xv0 = *(const float4*)(&xT[lr * XS + w * 8]);
                const float4 xv1 = *(const float4*)(&xT[lr * XS + w * 8 + 4]);
                const float wa[4] = {wv.x, wv.y, wv.z, wv.w};
                const float xa[8] = {xv0.x, xv0.y, xv0.z, xv0.w,
                                     xv1.x, xv1.y, xv1.z, xv1.w};
                #pragma unroll
                for (int cc = 0; cc < 4; ++cc)
                    #pragma unroll
                    for (int s = 0; s < 8; ++s)
                        acc[cc * 8 + s] = fmaf(wa[cc], xa[s], acc[cc * 8 + s]);
            }
        }
    }
    #undef WLD

    if (!act) return;
    #pragma unroll
    for (int i = 0; i < 32; ++i) {       // reduce over kq (lane bits 4-5)
        acc[i] += __shfl_xor(acc[i], 16);
        acc[i] += __shfl_xor(acc[i], 32);
    }
    if (kq != 0) return;                 // epilogue on kq==0 lanes only

    const float4 bv = *(const float4*)(b1 + a * HID_DIM + bcol + cg * 4);
    #pragma unroll
    for (int s = 0; s < 8; ++s) {        // dup-slot writes identical
        float4 v = make_float4(fmaxf(acc[0*8+s] + bv.x, 0.f),
                               fmaxf(acc[1*8+s] + bv.y, 0.f),
                               fmaxf(acc[2*8+s] + bv.z, 0.f),
                               fmaxf(acc[3*8+s] + bv.w, 0.f));
        *(float4*)(h_out + (size_t)s_sid[w * 8 + s] * HID_DIM + bcol + cg * 4) = v;
    }
}

// ---------------- K2: OUT = H @ W2[a] + b2[a]; router fused into y==0 -------
// grid (MAXCH, 8 tiles of 32 cols), 256 thr, 19.9 KB LDS -> high occupancy.
// Full-K accumulation -> direct float4 stores, no atomics, no workspace.
// y==0 blocks also compute r_logits from the SAME hT tiles (all 512 k-rows
// pass through LDS here): thread t owns (s=t>>3, ch=t&7); rw tile (2 KB)
// staged per pass, broadcast-read. Removes r_part entirely.
// Mapping 4x8: cg=t&7 (4 cols), kq=(t>>3)&7, w=t>>6 (8 samples).
extern "C" __global__ __launch_bounds__(256)
void k2_mlp2(const float* __restrict__ h, const float* __restrict__ W2,
             const float* __restrict__ b2, const float* __restrict__ rw,
             const int* __restrict__ raw,
             float* __restrict__ o_out, float* __restrict__ r_out)
{
    __shared__ float hT[64 * XS];        // 9 KB per-pass h tile
    __shared__ float wS[64 * 32];        // 8 KB per-pass W tile
    __shared__ float rwS[64 * N_CHILD];  // 2 KB per-pass router tile
    __shared__ int s_cnt[64], s_info[4], s_wsum[4], s_sid[SB];

    const int c = blockIdx.x;
    const int t = threadIdx.x;
    const int len = sort_chunk(raw, c, s_cnt, s_info, s_wsum, s_sid);
    if (len == 0) return;                // block-uniform
    const int a = s_info[0];
    const int bcol = blockIdx.y * 32;
    const bool router = (blockIdx.y == 0);

    const float* Wb  = W2 + (size_t)a * HID_DIM * OUT_DIM + bcol;
    const float* rwp = rw + (size_t)a * HID_DIM * N_CHILD;
    const int r2w  = t >> 3;             // W staging rows r2w, r2w+32
    const int c4   = (t & 7) * 4;
    const int hrow = t & 63;             // h staging: 64 consecutive k
    const int hsb  = (t >> 6) * 8;       // 8 samples per wave
    #define WLD2(P,I) (*(const float4*)(Wb + (size_t)((P)*64 + r2w + (I)*32) * OUT_DIM + c4))

    float4 wA0 = WLD2(0,0), wA1 = WLD2(0,1);
    float hA[8], hB[8];
    #pragma unroll
    for (int j = 0; j < 8; ++j)
        hA[j] = h[(size_t)s_sid[hsb + j] * HID_DIM + hrow];
    float rA0 = 0.f, rA1 = 0.f;
    if (router) { rA0 = rwp[t]; rA1 = rwp[256 + t]; }

    const int cg = t & 7;
    const int kq = (t >> 3) & 7;
    const int w  = t >> 6;
    const bool act = (w * 8) < len;
    const int rs  = t >> 3;              // router sample (0..31)
    const int rch = t & 7;               // router child

    float acc[32];
    #pragma unroll
    for (int i = 0; i < 32; ++i) acc[i] = 0.f;
    float racc = 0.f;

    for (int p = 0; p < 8; ++p) {        // 8 passes of 64 k-rows, full K=512
        __syncthreads();                 // tiles reusable
        #pragma unroll
        for (int j = 0; j < 8; ++j)
            hT[hrow * XS + hsb + j] = hA[j];
        *(float4*)(&wS[(r2w +  0) * 32 + c4]) = wA0;
        *(float4*)(&wS[(r2w + 32) * 32 + c4]) = wA1;
        if (router) { rwS[t] = rA0; rwS[256 + t] = rA1; }
        __syncthreads();
        if (p < 7) {                     // prefetch next tiles -> regs
            wA0 = WLD2(p+1,0); wA1 = WLD2(p+1,1);
            #pragma unroll
            for (int j = 0; j < 8; ++j)
                hB[j] = h[(size_t)s_sid[hsb + j] * HID_DIM + (p+1)*64 + hrow];
            if (router) {
                rA0 = rwp[(size_t)(p+1)*512 + t];
                rA1 = rwp[(size_t)(p+1)*512 + 256 + t];
            }
        }
        if (act) {
            #pragma unroll
            for (int i = 0; i < 8; ++i) {
                const int row = i * 8 + kq;
                const float4 wv  = *(const float4*)(&wS[row * 32 + cg * 4]);
                const float4 xv0 = *(const float4*)(&hT[row * XS + w * 8]);
                const float4 xv1 = *(const float4*)(&hT[row * XS + w * 8 + 4]);
                const float wa[4] = {wv.x, wv.y, wv.z, wv.w};
                const float xa[8] = {xv0.x, xv0.y, xv0.z, xv0.w,
                                     xv1.x, xv1.y, xv1.z, xv1.w};
                #pragma unroll
                for (int cc = 0; cc < 4; ++cc)
                    #pragma unroll
                    for (int s = 0; s < 8; ++s)
                        acc[cc * 8 + s] = fmaf(wa[cc], xa[s], acc[cc * 8 + s]);
            }
        }
        if (router) {                    // r_logits partial: hT broadcast-read
            #pragma unroll
            for (int row = 0; row < 64; ++row)
                racc = fmaf(hT[row * XS + rs], rwS[row * N_CHILD + rch], racc);
        }
        if (p < 7) {
            #pragma unroll
            for (int j = 0; j < 8; ++j) hA[j] = hB[j];
        }
    }
    #undef WLD2

    #pragma unroll
    for (int i = 0; i < 32; ++i) {       // reduce over kq (lane bits 3-5)
        acc[i] += __shfl_xor(acc[i], 8);
        acc[i] += __shfl_xor(acc[i], 16);
        acc[i] += __shfl_xor(acc[i], 32);
    }
    if (act && kq == 0) {
        const float4 bv = *(const float4*)(b2 + a * OUT_DIM + bcol + cg * 4);
        #pragma unroll
        for (int s = 0; s < 8; ++s) {
            const int g = w * 8 + s;
            if (g < len) {               // strict gating: one writer per row
                float4 v = make_float4(acc[0*8+s] + bv.x, acc[1*8+s] + bv.y,
                                       acc[2*8+s] + bv.z, acc[3*8+s] + bv.w);
                *(float4*)(o_out + (size_t)s_sid[g] * OUT_DIM + bcol + cg * 4) = v;
            }
        }
    }
    if (router && rs < len)              // direct store, no zeroing needed
        r_out[(size_t)s_sid[rs] * N_CHILD + rch] = racc;
}

extern "C" void kernel_launch(void* const* d_in, const int* in_sizes, int n_in,
                              void* d_out, int out_size, void* d_ws, size_t ws_size,
                              hipStream_t stream) {
    const float* x  = (const float*)d_in[0];
    const float* W1 = (const float*)d_in[1];
    const float* b1 = (const float*)d_in[2];
    const float* W2 = (const float*)d_in[3];
    const float* b2 = (const float*)d_in[4];
    const float* rw = (const float*)d_in[5];
    const int* raw  = (const int*)d_in[6];

    float* out   = (float*)d_out;
    float* h_out = out;                                   // [B, HID]
    float* o_out = h_out + (size_t)BATCH * HID_DIM;       // [B, OUT]
    float* r_out = o_out + (size_t)BATCH * OUT_DIM;       // [B, C]

    hipLaunchKernelGGL(k1_mlp1, dim3(MAXCH, 8), dim3(256), 0, stream,
                       x, W1, b1, raw, h_out);
    hipLaunchKernelGGL(k2_mlp2, dim3(MAXCH, 8), dim3(256), 0, stream,
                       h_out, W2, b2, rw, raw, o_out, r_out);
}